// Round 15
// baseline (41.589 us; speedup 1.0000x reference)
//
#include <hip/hip_runtime.h>
#include <math.h>

#define BLKSZ 160
#define NWT   64
#define WTLEN 512
#define FPB   24      // frames per main block
#define SPB   3840    // samples per main block (24*160); = 15 bs1-rows exactly
#define NTHR  768     // 12 waves
#define NBLK  250     // T / SPB
#define SMP   28      // smT row pitch (floats), 16B-aligned

// ReduceWindowRewriter(base_length=16) level sizes for T=960000
#define NB1   3750    // T/256
#define NB1P  3760    // padded to 235*16
#define NB2   235
#define NB2P  240
#define NB3   15      // < 16 -> naive sequential top scan

// f32 increment exactly as the reference: (pitch / 16000) * 512
static __device__ __forceinline__ float inc32_of(float p) {
    return (p / 16000.0f) * 512.0f;
}

// K0: wts_eff (rows 0..3 raw, 4..63 tanh) + barrier counter reset
__global__ __launch_bounds__(256) void k_prep(
    const float* __restrict__ wts, float* __restrict__ wts_eff,
    unsigned int* __restrict__ counter)
{
    if (blockIdx.x == 128) {
        if (threadIdx.x == 0) counter[0] = 0u;
        return;
    }
    int i = blockIdx.x * 256 + threadIdx.x;       // 128*256 = 32768 exactly
    float v = wts[i];
    if ((i >> 9) >= 4) v = tanhf(v);
    wts_eff[i] = v;
}

// K1: everything else, with an internal device barrier publishing bs1
__global__ __launch_bounds__(768, 3) void k_fused(
    const float* __restrict__ pitch, const float* __restrict__ amp,
    const float* __restrict__ att, const float* __restrict__ wts_eff,
    float* __restrict__ bs1g, unsigned int* __restrict__ counter,
    float* __restrict__ out, int frames)
{
    __shared__ float smT[NWT][SMP];         // 7 KB: transposed weights, padded rows
    __shared__ float mixrow[FPB][WTLEN];    // 48 KB; head doubles as bs1L (3760 f)
    __shared__ float pr[SPB];               // 15 KB: inc -> within-16 prefix in place
    __shared__ float roffL[SPB / 16];       // 240
    __shared__ float bs2L[NB2P];            // zero-padded
    __shared__ float bs3L[NB3];
    __shared__ float S4L[NB3];
    __shared__ float S3w[2];
    __shared__ float S2w[16];
    __shared__ float bs1prevL;

    float* bs1L = &mixrow[0][0];            // overlay: dead before mixrow write

    int tid = threadIdx.x, lane = tid & 63, wv = tid >> 6;   // wv in [0,12)
    int b = blockIdx.x;
    int f0 = b * FPB;
    size_t base = (size_t)b * SPB;
    int j0 = 15 * b - 2;                    // S2 window start
    int rlo = max(j0, 0) >> 4;              // bs1-row window base for S2

    // ---- softmax: 12 waves x 2 frames; lane = wavetable, write transposed ----
    #pragma unroll
    for (int r = 0; r < 2; ++r) {
        int f = f0 + wv * 2 + r;
        float a = att[(size_t)lane * frames + f];
        float m = a;
        #pragma unroll
        for (int off = 32; off; off >>= 1) m = fmaxf(m, __shfl_xor(m, off, 64));
        float e = expf(a - m);
        float s = e;
        #pragma unroll
        for (int off = 32; off; off >>= 1) s += __shfl_xor(s, off, 64);
        smT[lane][wv * 2 + r] = e / s;
    }

    // ---- stage incs (regs + LDS) ----
    float increg[SPB / NTHR];
    #pragma unroll
    for (int i = 0; i < SPB / NTHR; ++i) {
        increg[i] = inc32_of(pitch[base + i * NTHR + tid]);
        pr[i * NTHR + tid] = increg[i];
    }
    __syncthreads();

    // ---- within-16 prefixes (240 thr), in place ----
    if (tid < SPB / 16) {
        int bofs = tid * 16;
        float acc = pr[bofs];
        for (int j = 1; j < 16; ++j) { acc = acc + pr[bofs + j]; pr[bofs + j] = acc; }
    }
    __syncthreads();

    // ---- this block's 15 bs1 values -> global (chains over bs0 = pr tails) ----
    if (tid < 15) {
        float acc = pr[(tid * 16) * 16 + 15];
        for (int q = 1; q < 16; ++q) acc = acc + pr[(tid * 16 + q) * 16 + 15];
        bs1g[15 * b + tid] = acc;
    }
    __syncthreads();                        // all bs1 stores drained (vmcnt)

    // ---- device barrier: arrive + spin (one thread), others park on sync ----
    if (tid == 0) {
        __threadfence();                    // flush this CU/XCD writes device-wide
        __hip_atomic_fetch_add(&counter[0], 1u, __ATOMIC_RELEASE,
                               __HIP_MEMORY_SCOPE_AGENT);
        while (__hip_atomic_load(&counter[0], __ATOMIC_ACQUIRE,
                                 __HIP_MEMORY_SCOPE_AGENT) < (unsigned)NBLK) {
            __builtin_amdgcn_s_sleep(8);
        }
    }
    __syncthreads();

    // ---- all bs1 -> LDS overlay via agent-coherent loads (stale-L2-proof) ----
    for (int i = tid; i < NB1P; i += NTHR) {
        float v = 0.f;
        if (i < NB1)
            v = __hip_atomic_load(&bs1g[i], __ATOMIC_RELAXED,
                                  __HIP_MEMORY_SCOPE_AGENT);
        bs1L[i] = v;
    }
    __syncthreads();

    // ---- bs2: chain of 16 bs1 (240 thr, pad rows -> 0) ----
    if (tid < NB2P) {
        float a = 0.f;
        if (tid < NB2) {
            a = bs1L[tid * 16];
            for (int j = 1; j < 16; ++j) a = a + bs1L[tid * 16 + j];
        }
        bs2L[tid] = a;
    }
    __syncthreads();
    // ---- bs3: chain of 16 bs2 ----
    if (tid < NB3) {
        float a = bs2L[tid * 16];
        for (int j = 1; j < 16; ++j) a = a + bs2L[tid * 16 + j];
        bs3L[tid] = a;
    }
    __syncthreads();
    // ---- S4: naive sequential scan (15 < 16) ----
    if (tid == 0) {
        float a = 0.f;
        for (int i = 0; i < NB3; ++i) { a = a + bs3L[i]; S4L[i] = a; }
    }
    __syncthreads();
    // ---- the two S3 values this block needs ----
    if (tid < 2) {
        int r = rlo - 1 + tid;
        float v = 0.f;
        if (r >= 0 && r < NB2) {
            int g = r >> 4, p = r & 15;
            float a = bs2L[g * 16];
            for (int k = 1; k <= p; ++k) a = a + bs2L[g * 16 + k];
            v = g ? (a + S4L[g - 1]) : a;
        }
        S3w[tid] = v;
    }
    if (tid == 2) bs1prevL = (b > 0) ? bs1L[15 * b - 1] : 0.f;
    __syncthreads();
    // ---- the 16 S2 values: S2[j] = inner2(j) + S3[(j>>4)-1] ----
    if (tid < 16) {
        int j = j0 + tid;
        float v = 0.f;
        if (j >= 0) {
            int r = j >> 4, p = j & 15;
            float a = bs1L[r * 16];
            for (int q = 1; q <= p; ++q) a = a + bs1L[r * 16 + q];
            v = r ? (a + S3w[r - rlo]) : a;
        }
        S2w[tid] = v;
    }
    __syncthreads();    // bs1L dead from here on

    // ---- roffL (240 thr) || mixrow (all threads; overwrites overlay) ----
    if (tid < SPB / 16) {
        float v;
        if (tid == 0) {
            v = (b == 0) ? 0.f : (bs1prevL + S2w[0]);
        } else {
            int lr = (tid - 1) >> 4;
            int p  = (tid - 1) & 15;
            float acc = pr[(lr * 16) * 16 + 15];
            for (int q = 1; q <= p; ++q) acc = acc + pr[(lr * 16 + q) * 16 + 15];
            int gr = 15 * b + lr;
            v = gr ? (acc + S2w[lr + 1]) : acc;
        }
        roffL[tid] = v;
    }
    {
        // 1536 items = (fgroup 0..2) x (j 0..511); thread does items tid, tid+768.
        #pragma unroll
        for (int it = 0; it < 2; ++it) {
            int item = tid + it * NTHR;
            int fg = item >> 9;             // 0..2
            int j  = item & 511;
            float acc[8];
            #pragma unroll
            for (int k = 0; k < 8; ++k) acc[k] = 0.f;
            for (int w = 0; w < NWT; ++w) {
                float v = wts_eff[w * WTLEN + j];
                float4 s0 = *(const float4*)&smT[w][fg * 8];
                float4 s1 = *(const float4*)&smT[w][fg * 8 + 4];
                acc[0] += s0.x * v;  acc[1] += s0.y * v;
                acc[2] += s0.z * v;  acc[3] += s0.w * v;
                acc[4] += s1.x * v;  acc[5] += s1.y * v;
                acc[6] += s1.z * v;  acc[7] += s1.w * v;
            }
            #pragma unroll
            for (int k = 0; k < 8; ++k) mixrow[fg * 8 + k][j] = acc[k];
        }
    }
    __syncthreads();

    // ---- per-sample: C = fl(prefix + roff); idx = (C-inc) % 512; lerp; amp ----
    #pragma unroll
    for (int i = 0; i < SPB / NTHR; ++i) {
        int tl = i * NTHR + tid;
        size_t tg = base + tl;
        float C = pr[tl] + roffL[tl >> 4];
        float sub = C - increg[i];
        float idx = fmodf(sub, 512.0f);
        if (idx < 0.f) idx += 512.f;
        int li = (int)idx;
        float alpha = idx - (float)li;
        int hi = ((int)ceilf(idx)) & (WTLEN - 1);
        int fr = tl / BLKSZ;
        float wlo = mixrow[fr][li];
        float whi = mixrow[fr][hi];
        out[tg] = (wlo + alpha * (whi - wlo)) * amp[tg];
    }
}

extern "C" void kernel_launch(void* const* d_in, const int* in_sizes, int n_in,
                              void* d_out, int out_size, void* d_ws, size_t ws_size,
                              hipStream_t stream) {
    const float* pitch = (const float*)d_in[0];
    const float* amp   = (const float*)d_in[1];
    const float* wts   = (const float*)d_in[2];
    const float* att   = (const float*)d_in[3];

    int T      = in_sizes[0];        // 960000
    int frames = T / BLKSZ;          // 6000

    float* ws      = (float*)d_ws;
    float* wts_eff = ws;                       // 32768 floats
    float* bs1     = ws + 32768;               // 3750 floats (pad 3840)
    unsigned int* counter = (unsigned int*)(ws + 32768 + 3840);
    float* out     = (float*)d_out;

    k_prep <<<129, 256, 0, stream>>>(wts, wts_eff, counter);
    k_fused<<<NBLK, NTHR, 0, stream>>>(pitch, amp, att, wts_eff, bs1, counter,
                                       out, frames);
}